// Round 1
// baseline (851.363 us; speedup 1.0000x reference)
//
#include <hip/hip_runtime.h>

typedef _Float16 F16;
typedef __attribute__((ext_vector_type(8))) _Float16 f16x8;
typedef __attribute__((ext_vector_type(4))) _Float16 f16x4;
typedef __attribute__((ext_vector_type(4))) float f32x4;

constexpr int NTOK = 8192;   // B*T
constexpr int C    = 1024;   // d_model
constexpr int FF   = 2048;   // d_ff
constexpr int NE   = 8;      // experts
constexpr int BM   = 128;
constexpr int BK   = 64;
constexpr int MAXT = 136;          // max routed row-tiles: 16384/128 + 8
constexpr int RCAP = MAXT * 128;   // 17408 padded routed rows
constexpr int SBASE = RCAP;        // shared-expert rows start here in H
constexpr int ROWS = RCAP + NTOK;  // 25600

// meta layout (ints): [0..8) cnt, [8..16) cursor, [16..24) base, [24] ntiles,
// [32..32+MAXT) tile_expert, [32+MAXT..32+2*MAXT) tile_row0
#define MI_CNT 0
#define MI_CUR 8
#define MI_BASE 16
#define MI_NT 24
#define MI_TE 32
#define MI_TR (32 + MAXT)

__device__ __forceinline__ void gload16(const void* g, void* l) {
  // async global->LDS, 16B per lane; LDS dest is wave-uniform base + lane*16
  __builtin_amdgcn_global_load_lds(
      (__attribute__((address_space(1))) void*)g,
      (__attribute__((address_space(3))) void*)l, 16, 0, 0);
}

// ---------------- cast x (fp32 -> fp16) ----------------
__global__ __launch_bounds__(256) void k_cast_x(const float* __restrict__ x,
                                                F16* __restrict__ xh) {
  int i = blockIdx.x * blockDim.x + threadIdx.x;   // group of 4 elems
  float4 v = ((const float4*)x)[i];
  f16x4 o;
  o.x = (F16)v.x; o.y = (F16)v.y; o.z = (F16)v.z; o.w = (F16)v.w;
  ((f16x4*)xh)[i] = o;
}

// ------------- transpose+cast weights: src [K][N] fp32 -> dst [N][K] fp16 ----
// grid.z = 9: z<8 -> w8 + z*K*N, z==8 -> w1 (shared-expert weight)
__global__ __launch_bounds__(256) void k_cast_wt(const float* __restrict__ w8,
                                                 const float* __restrict__ w1,
                                                 F16* __restrict__ dstb,
                                                 int K, int N) {
  int z = blockIdx.z;
  const float* src = (z < NE) ? (w8 + (size_t)z * K * N) : w1;
  F16* dst = dstb + (size_t)z * N * K;
  __shared__ float t[32][33];
  int n0 = blockIdx.x * 32, k0 = blockIdx.y * 32;
  int tx = threadIdx.x & 31, ty = threadIdx.x >> 5;   // ty in [0,8)
#pragma unroll
  for (int i = 0; i < 4; i++)
    t[ty + i * 8][tx] = src[(size_t)(k0 + ty + i * 8) * N + n0 + tx];
  __syncthreads();
#pragma unroll
  for (int i = 0; i < 4; i++)
    dst[(size_t)(n0 + ty + i * 8) * K + k0 + tx] = (F16)t[tx][ty + i * 8];
}

// ---------------- router: fp64 logits, top-2, softmax ----------------
__global__ __launch_bounds__(256) void k_router(const float* __restrict__ x,
                                                const float* __restrict__ rw,
                                                int* __restrict__ meta,
                                                int* __restrict__ te0, int* __restrict__ te1,
                                                float* __restrict__ tw0, float* __restrict__ tw1) {
  __shared__ float lrw[NE * C];
  for (int i = threadIdx.x; i < NE * C / 4; i += 256)
    ((float4*)lrw)[i] = ((const float4*)rw)[i];
  __syncthreads();
  int lane = threadIdx.x & 63, wid = threadIdx.x >> 6;
  int t = blockIdx.x * 4 + wid;
  const float* xr = x + (size_t)t * C;
  float xv[16];
#pragma unroll
  for (int i = 0; i < 4; i++) {
    float4 v = ((const float4*)xr)[lane * 4 + i];
    xv[i * 4 + 0] = v.x; xv[i * 4 + 1] = v.y; xv[i * 4 + 2] = v.z; xv[i * 4 + 3] = v.w;
  }
  double lg[NE];
#pragma unroll
  for (int e = 0; e < NE; e++) {
    double s = 0.0;
#pragma unroll
    for (int i = 0; i < 16; i++)
      s += (double)xv[i] * (double)lrw[e * C + lane * 16 + i];
#pragma unroll
    for (int d = 1; d < 64; d <<= 1) s += __shfl_xor(s, d, 64);
    lg[e] = s;
  }
  // top-2, first-occurrence tie-break (matches top_k)
  double b0 = -1e300; int i0 = 0;
#pragma unroll
  for (int e = 0; e < NE; e++) if (lg[e] > b0) { b0 = lg[e]; i0 = e; }
  double b1 = -1e300; int i1 = 0;
#pragma unroll
  for (int e = 0; e < NE; e++) if (e != i0 && lg[e] > b1) { b1 = lg[e]; i1 = e; }
  float ex = __expf((float)(b1 - b0));
  float w0 = 1.f / (1.f + ex), w1 = ex / (1.f + ex);
  if (lane == 0) {
    te0[t] = i0; te1[t] = i1; tw0[t] = w0; tw1[t] = w1;
    atomicAdd(&meta[MI_CNT + i0], 1);
    atomicAdd(&meta[MI_CNT + i1], 1);
  }
}

// ---------------- scan: bases, tile map, pad fill ----------------
__global__ __launch_bounds__(256) void k_scan(int* __restrict__ meta,
                                              int* __restrict__ rowtok,
                                              float* __restrict__ roww) {
  __shared__ int s_cnt[NE], s_base[NE];
  if (threadIdx.x == 0) {
    int b = 0, nt = 0;
    for (int e = 0; e < NE; e++) {
      int c = meta[MI_CNT + e];
      s_cnt[e] = c; s_base[e] = b;
      meta[MI_BASE + e] = b;
      meta[MI_CUR + e] = 0;
      int tiles = (c + 127) >> 7;
      for (int t = 0; t < tiles; t++) {
        meta[MI_TE + nt] = e;
        meta[MI_TR + nt] = b + t * 128;
        nt++;
      }
      b += tiles << 7;
    }
    for (int t = nt; t < MAXT; t++) meta[MI_TE + t] = -1;
    meta[MI_NT] = nt;
  }
  __syncthreads();
  for (int e = 0; e < NE; e++) {
    int c = s_cnt[e], b = s_base[e];
    int al = (c + 127) & ~127;
    for (int i = c + threadIdx.x; i < al; i += 256) {
      rowtok[b + i] = -1;
      roww[b + i] = 0.f;
    }
  }
}

// ---------------- scatter tokens into expert buckets ----------------
__global__ __launch_bounds__(256) void k_scatter(const int* __restrict__ te0,
                                                 const int* __restrict__ te1,
                                                 const float* __restrict__ tw0,
                                                 const float* __restrict__ tw1,
                                                 int* __restrict__ meta,
                                                 int* __restrict__ rowtok,
                                                 float* __restrict__ roww) {
  int t = blockIdx.x * 256 + threadIdx.x;
  int e0 = te0[t], e1 = te1[t];
  int p0 = atomicAdd(&meta[MI_CUR + e0], 1);
  int r0 = meta[MI_BASE + e0] + p0;
  rowtok[r0] = t; roww[r0] = tw0[t];
  int p1 = atomicAdd(&meta[MI_CUR + e1], 1);
  int r1 = meta[MI_BASE + e1] + p1;
  rowtok[r1] = t; roww[r1] = tw1[t];
}

// ---------------- GEMM1: H = silu(X Wg) * (X Wu), fp16 out ----------------
// A: gathered x rows [128 x 64], B: Wg^T/Wu^T tiles [128n x 64k]
template <bool SHARED>
__global__ __launch_bounds__(256, 2) void k_gemm1(const F16* __restrict__ xh,
                                                  const F16* __restrict__ wg,
                                                  const F16* __restrict__ wu,
                                                  F16* __restrict__ H,
                                                  const int* __restrict__ meta,
                                                  const int* __restrict__ rowtok) {
  int e, row0;
  if (SHARED) { e = NE; row0 = SBASE + blockIdx.y * BM; }
  else {
    e = meta[MI_TE + blockIdx.y];
    if (e < 0) return;
    row0 = meta[MI_TR + blockIdx.y];
  }
  const int n0 = blockIdx.x * 128;
  const F16* BG = wg + (size_t)e * FF * C;
  const F16* BU = wu + (size_t)e * FF * C;
  __shared__ __align__(16) F16 sA[128 * 64], sG[128 * 64], sU[128 * 64];
  const int lane = threadIdx.x & 63, wid = threadIdx.x >> 6;
  const int c8 = (lane & 7) << 3, rsub = lane >> 3;

  const F16 *asrc[4], *gsrc[4], *usrc[4];
#pragma unroll
  for (int p = 0; p < 4; ++p) {
    int r = p * 32 + wid * 8 + rsub;
    int tok;
    if (SHARED) tok = row0 - SBASE + r;
    else { tok = rowtok[row0 + r]; if (tok < 0) tok = 0; }  // pad rows: harmless dup
    asrc[p] = xh + (size_t)tok * C + c8;
    int n = n0 + p * 32 + wid * 8 + rsub;
    gsrc[p] = BG + (size_t)n * C + c8;
    usrc[p] = BU + (size_t)n * C + c8;
  }

  f32x4 accg[4][4], accu[4][4];
  const f32x4 fz = {0.f, 0.f, 0.f, 0.f};
#pragma unroll
  for (int i = 0; i < 4; i++)
#pragma unroll
    for (int j = 0; j < 4; j++) { accg[i][j] = fz; accu[i][j] = fz; }

  const int mrow = (wid >> 1) << 6, ncol = (wid & 1) << 6;
  const int fro = lane & 15, fk = (lane >> 4) << 3;

  for (int k0 = 0; k0 < C; k0 += BK) {
#pragma unroll
    for (int p = 0; p < 4; ++p) {
      int rb = p * 32 + wid * 8;   // wave-uniform LDS row base
      gload16(asrc[p] + k0, &sA[rb * 64]);
      gload16(gsrc[p] + k0, &sG[rb * 64]);
      gload16(usrc[p] + k0, &sU[rb * 64]);
    }
    __syncthreads();
#pragma unroll
    for (int kk = 0; kk < BK; kk += 32) {
      f16x8 a[4], g[4], u[4];
#pragma unroll
      for (int i = 0; i < 4; ++i) {
        a[i] = *(const f16x8*)&sA[(mrow + i * 16 + fro) * 64 + kk + fk];
        g[i] = *(const f16x8*)&sG[(ncol + i * 16 + fro) * 64 + kk + fk];
        u[i] = *(const f16x8*)&sU[(ncol + i * 16 + fro) * 64 + kk + fk];
      }
#pragma unroll
      for (int mi = 0; mi < 4; ++mi)
#pragma unroll
        for (int ni = 0; ni < 4; ++ni) {
          accg[mi][ni] = __builtin_amdgcn_mfma_f32_16x16x32_f16(a[mi], g[ni], accg[mi][ni], 0, 0, 0);
          accu[mi][ni] = __builtin_amdgcn_mfma_f32_16x16x32_f16(a[mi], u[ni], accu[mi][ni], 0, 0, 0);
        }
    }
    __syncthreads();
  }

  const int erow = (lane >> 4) << 2, ecol = lane & 15;
#pragma unroll
  for (int mi = 0; mi < 4; ++mi)
#pragma unroll
    for (int ni = 0; ni < 4; ++ni)
#pragma unroll
      for (int j = 0; j < 4; ++j) {
        int grow = row0 + mrow + mi * 16 + erow + j;
        int gcol = n0 + ncol + ni * 16 + ecol;
        float gv = accg[mi][ni][j], uv = accu[mi][ni][j];
        float h = gv / (1.f + __expf(-gv)) * uv;   // silu(g)*u
        H[(size_t)grow * FF + gcol] = (F16)h;
      }
}

// ---------------- GEMM2: Y = H Wd, scaled scatter-add into out ----------------
template <bool SHARED>
__global__ __launch_bounds__(256, 2) void k_gemm2(const F16* __restrict__ H,
                                                  const F16* __restrict__ wd,
                                                  float* __restrict__ out,
                                                  const int* __restrict__ meta,
                                                  const int* __restrict__ rowtok,
                                                  const float* __restrict__ roww) {
  int e, row0;
  if (SHARED) { e = NE; row0 = SBASE + blockIdx.y * BM; }
  else {
    e = meta[MI_TE + blockIdx.y];
    if (e < 0) return;
    row0 = meta[MI_TR + blockIdx.y];
  }
  const int n0 = blockIdx.x * 128;             // over C=1024
  const F16* BD = wd + (size_t)e * C * FF;     // [1024 n][2048 k]
  __shared__ __align__(16) F16 sA[128 * 64], sB[128 * 64];
  const int lane = threadIdx.x & 63, wid = threadIdx.x >> 6;
  const int c8 = (lane & 7) << 3, rsub = lane >> 3;

  const F16 *asrc[4], *bsrc[4];
#pragma unroll
  for (int p = 0; p < 4; ++p) {
    int r = p * 32 + wid * 8 + rsub;
    asrc[p] = H + (size_t)(row0 + r) * FF + c8;
    bsrc[p] = BD + (size_t)(n0 + p * 32 + wid * 8 + rsub) * FF + c8;
  }

  f32x4 acc[4][4];
  const f32x4 fz = {0.f, 0.f, 0.f, 0.f};
#pragma unroll
  for (int i = 0; i < 4; i++)
#pragma unroll
    for (int j = 0; j < 4; j++) acc[i][j] = fz;

  const int mrow = (wid >> 1) << 6, ncol = (wid & 1) << 6;
  const int fro = lane & 15, fk = (lane >> 4) << 3;

  for (int k0 = 0; k0 < FF; k0 += BK) {
#pragma unroll
    for (int p = 0; p < 4; ++p) {
      int rb = p * 32 + wid * 8;
      gload16(asrc[p] + k0, &sA[rb * 64]);
      gload16(bsrc[p] + k0, &sB[rb * 64]);
    }
    __syncthreads();
#pragma unroll
    for (int kk = 0; kk < BK; kk += 32) {
      f16x8 a[4], b[4];
#pragma unroll
      for (int i = 0; i < 4; ++i) {
        a[i] = *(const f16x8*)&sA[(mrow + i * 16 + fro) * 64 + kk + fk];
        b[i] = *(const f16x8*)&sB[(ncol + i * 16 + fro) * 64 + kk + fk];
      }
#pragma unroll
      for (int mi = 0; mi < 4; ++mi)
#pragma unroll
        for (int ni = 0; ni < 4; ++ni)
          acc[mi][ni] = __builtin_amdgcn_mfma_f32_16x16x32_f16(a[mi], b[ni], acc[mi][ni], 0, 0, 0);
    }
    __syncthreads();
  }

  const int erow = (lane >> 4) << 2, ecol = lane & 15;
#pragma unroll
  for (int mi = 0; mi < 4; ++mi)
#pragma unroll
    for (int j = 0; j < 4; ++j) {
      int grow = row0 + mrow + mi * 16 + erow + j;
      int tok; float w;
      if (SHARED) { tok = grow - SBASE; w = 1.f; }
      else { tok = rowtok[grow]; w = (tok >= 0) ? roww[grow] : 0.f; }
      if (tok >= 0) {
        float* orow = out + (size_t)tok * C + n0 + ncol + ecol;
#pragma unroll
        for (int ni = 0; ni < 4; ++ni) {
          float v = acc[mi][ni][j] * w;
          if (SHARED) orow[ni * 16] = v;        // first writer: full overwrite
          else atomicAdd(&orow[ni * 16], v);    // routed experts accumulate
        }
      }
    }
}

// ---------------- host launch ----------------
extern "C" void kernel_launch(void* const* d_in, const int* in_sizes, int n_in,
                              void* d_out, int out_size, void* d_ws, size_t ws_size,
                              hipStream_t stream) {
  const float* x  = (const float*)d_in[0];
  const float* rw = (const float*)d_in[1];
  const float* wgate = (const float*)d_in[2];
  const float* wup   = (const float*)d_in[3];
  const float* wdown = (const float*)d_in[4];
  const float* sg = (const float*)d_in[5];
  const float* su = (const float*)d_in[6];
  const float* sd = (const float*)d_in[7];
  float* out = (float*)d_out;

  char* ws = (char*)d_ws;
  size_t o = 0;
  auto alloc = [&](size_t bytes) -> void* {
    void* p = ws + o;
    o += (bytes + 255) & ~(size_t)255;
    return p;
  };
  F16* xh = (F16*)alloc((size_t)NTOK * C * 2);
  F16* WG = (F16*)alloc((size_t)9 * FF * C * 2);
  F16* WU = (F16*)alloc((size_t)9 * FF * C * 2);
  F16* WD = (F16*)alloc((size_t)9 * C * FF * 2);
  F16* H  = (F16*)alloc((size_t)ROWS * FF * 2);
  int* rowtok = (int*)alloc((size_t)RCAP * 4);
  float* roww = (float*)alloc((size_t)RCAP * 4);
  int* meta = (int*)alloc(2048);
  int* te0 = (int*)alloc((size_t)NTOK * 4);
  int* te1 = (int*)alloc((size_t)NTOK * 4);
  float* tw0 = (float*)alloc((size_t)NTOK * 4);
  float* tw1 = (float*)alloc((size_t)NTOK * 4);
  if (o > ws_size) return;  // workspace too small: visible clean failure

  hipMemsetAsync(meta, 0, 2048, stream);
  k_cast_x<<<NTOK * C / 1024, 256, 0, stream>>>(x, xh);
  k_cast_wt<<<dim3(FF / 32, C / 32, 9), 256, 0, stream>>>(wgate, sg, WG, C, FF);
  k_cast_wt<<<dim3(FF / 32, C / 32, 9), 256, 0, stream>>>(wup, su, WU, C, FF);
  k_cast_wt<<<dim3(C / 32, FF / 32, 9), 256, 0, stream>>>(wdown, sd, WD, FF, C);
  k_router<<<NTOK / 4, 256, 0, stream>>>(x, rw, meta, te0, te1, tw0, tw1);
  k_scan<<<1, 256, 0, stream>>>(meta, rowtok, roww);
  k_scatter<<<NTOK / 256, 256, 0, stream>>>(te0, te1, tw0, tw1, meta, rowtok, roww);
  k_gemm1<false><<<dim3(FF / 128, MAXT), 256, 0, stream>>>(xh, WG, WU, H, meta, rowtok);
  k_gemm1<true><<<dim3(FF / 128, NTOK / 128), 256, 0, stream>>>(xh, WG, WU, H, meta, rowtok);
  k_gemm2<true><<<dim3(C / 128, NTOK / 128), 256, 0, stream>>>(H, WD, out, meta, rowtok, roww);
  k_gemm2<false><<<dim3(C / 128, MAXT), 256, 0, stream>>>(H, WD, out, meta, rowtok, roww);
}

// Round 2
// 833.182 us; speedup vs baseline: 1.0218x; 1.0218x over previous
//
#include <hip/hip_runtime.h>

typedef _Float16 F16;
typedef __attribute__((ext_vector_type(8))) _Float16 f16x8;
typedef __attribute__((ext_vector_type(4))) _Float16 f16x4;
typedef __attribute__((ext_vector_type(4))) float f32x4;

constexpr int NTOK = 8192;   // B*T
constexpr int C    = 1024;   // d_model
constexpr int FF   = 2048;   // d_ff
constexpr int NE   = 8;      // experts
constexpr int NRT  = 72;     // max routed 256-row tiles: 16384/256 + 8
constexpr int NST  = 32;     // shared-expert tiles: 8192/256
constexpr int MAXT = NRT + NST;     // 104
constexpr int SBASE = NRT * 256;    // 18432: shared rows start here in H/Y
constexpr int ROWS = SBASE + NTOK;  // 26624

// meta ints: [0..8) cnt, [8..16) cursor, [16..24) base, [32..32+MAXT) tile_e,
// [32+MAXT..32+2*MAXT) tile_row0
#define MI_CNT 0
#define MI_CUR 8
#define MI_BASE 16
#define MI_TE 32
#define MI_TR (32 + MAXT)

__device__ __forceinline__ void gload16(const void* g, void* l) {
  // async global->LDS: LDS dest is wave-uniform base + lane*16; global src per-lane
  __builtin_amdgcn_global_load_lds(
      (__attribute__((address_space(1))) void*)g,
      (__attribute__((address_space(3))) void*)l, 16, 0, 0);
}
__device__ __forceinline__ void vmcnt2() { asm volatile("s_waitcnt vmcnt(2)" ::: "memory"); }
__device__ __forceinline__ void vmcnt0() { asm volatile("s_waitcnt vmcnt(0)" ::: "memory"); }
__device__ __forceinline__ void lgkm0() { asm volatile("s_waitcnt lgkmcnt(0)" ::: "memory"); }
#define SCHB() __builtin_amdgcn_sched_barrier(0)
#define BARR() __builtin_amdgcn_s_barrier()

// ---------------- cast x (fp32 -> fp16) ----------------
__global__ __launch_bounds__(256) void k_cast_x(const float* __restrict__ x,
                                                F16* __restrict__ xh) {
  int i = blockIdx.x * blockDim.x + threadIdx.x;   // group of 4 elems
  float4 v = ((const float4*)x)[i];
  f16x4 o;
  o.x = (F16)v.x; o.y = (F16)v.y; o.z = (F16)v.z; o.w = (F16)v.w;
  ((f16x4*)xh)[i] = o;
}

// ------- transpose+cast: src [K][N] fp32 -> dst [N'][K] fp16 ----------------
// MODE 0: N'=N (w_down). MODE 1: gate/up 16-col interleave into WGU:
//   n' = ((n>>4)<<5) | (sel<<4) | (n&15);  z = e*2+sel, e==8 -> shared weights
template <int MODE>
__global__ __launch_bounds__(256) void k_cast_w(const float* __restrict__ w8a,
                                                const float* __restrict__ w1a,
                                                const float* __restrict__ w8b,
                                                const float* __restrict__ w1b,
                                                F16* __restrict__ dst, int K, int N) {
  int z = blockIdx.z;
  const float* src; F16* d; int sel = 0;
  if (MODE == 1) {
    int e = z >> 1; sel = z & 1;
    src = sel ? ((e < NE) ? w8b + (size_t)e * K * N : w1b)
              : ((e < NE) ? w8a + (size_t)e * K * N : w1a);
    d = dst + (size_t)e * 2 * N * K;
  } else {
    src = (z < NE) ? (w8a + (size_t)z * K * N) : w1a;
    d = dst + (size_t)z * N * K;
  }
  __shared__ float t[64][33];
  int n0 = blockIdx.x * 32, k0 = blockIdx.y * 64;
  int tx = threadIdx.x & 31, ty = threadIdx.x >> 5;   // read: col tx, rows ty+8i
#pragma unroll
  for (int i = 0; i < 8; i++)
    t[ty + i * 8][tx] = src[(size_t)(k0 + ty + i * 8) * N + n0 + tx];
  __syncthreads();
  int wx = threadIdx.x & 63, wy = threadIdx.x >> 6;   // write: n-row wy+4i, col k wx
#pragma unroll
  for (int i = 0; i < 8; i++) {
    int n = n0 + wy + i * 4;
    size_t row = (MODE == 1) ? (size_t)(((n >> 4) << 5) | (sel << 4) | (n & 15))
                             : (size_t)n;
    d[row * K + k0 + wx] = (F16)t[wx][wy + i * 4];
  }
}

// ---------------- router: fp64 logits, top-2, softmax ----------------
__global__ __launch_bounds__(256) void k_router(const float* __restrict__ x,
                                                const float* __restrict__ rw,
                                                int* __restrict__ meta,
                                                int* __restrict__ te0, int* __restrict__ te1,
                                                float* __restrict__ tw0, float* __restrict__ tw1) {
  __shared__ float lrw[NE * C];
  for (int i = threadIdx.x; i < NE * C / 4; i += 256)
    ((float4*)lrw)[i] = ((const float4*)rw)[i];
  __syncthreads();
  int lane = threadIdx.x & 63, wid = threadIdx.x >> 6;
  int t = blockIdx.x * 4 + wid;
  const float* xr = x + (size_t)t * C;
  float xv[16];
#pragma unroll
  for (int i = 0; i < 4; i++) {
    float4 v = ((const float4*)xr)[lane * 4 + i];
    xv[i * 4 + 0] = v.x; xv[i * 4 + 1] = v.y; xv[i * 4 + 2] = v.z; xv[i * 4 + 3] = v.w;
  }
  double lg[NE];
#pragma unroll
  for (int e = 0; e < NE; e++) {
    double s = 0.0;
#pragma unroll
    for (int i = 0; i < 16; i++)
      s += (double)xv[i] * (double)lrw[e * C + lane * 16 + i];
#pragma unroll
    for (int d = 1; d < 64; d <<= 1) s += __shfl_xor(s, d, 64);
    lg[e] = s;
  }
  double b0 = -1e300; int i0 = 0;
#pragma unroll
  for (int e = 0; e < NE; e++) if (lg[e] > b0) { b0 = lg[e]; i0 = e; }
  double b1 = -1e300; int i1 = 0;
#pragma unroll
  for (int e = 0; e < NE; e++) if (e != i0 && lg[e] > b1) { b1 = lg[e]; i1 = e; }
  float ex = __expf((float)(b1 - b0));
  float w0 = 1.f / (1.f + ex), w1 = ex / (1.f + ex);
  if (lane == 0) {
    te0[t] = i0; te1[t] = i1; tw0[t] = w0; tw1[t] = w1;
    atomicAdd(&meta[MI_CNT + i0], 1);
    atomicAdd(&meta[MI_CNT + i1], 1);
  }
}

// ---------------- scan: bases, tile map (routed + shared), pad fill ----------
__global__ __launch_bounds__(256) void k_scan(int* __restrict__ meta,
                                              int* __restrict__ rowtok) {
  __shared__ int s_cnt[NE], s_base[NE];
  if (threadIdx.x == 0) {
    int b = 0, nt = 0;
    for (int e = 0; e < NE; e++) {
      int c = meta[MI_CNT + e];
      s_cnt[e] = c; s_base[e] = b;
      meta[MI_BASE + e] = b;
      meta[MI_CUR + e] = 0;
      int tiles = (c + 255) >> 8;
      for (int t = 0; t < tiles; t++) {
        meta[MI_TE + nt] = e;
        meta[MI_TR + nt] = b + t * 256;
        nt++;
      }
      b += tiles << 8;
    }
    for (int t = nt; t < NRT; t++) meta[MI_TE + t] = -1;
    for (int t = 0; t < NST; t++) {
      meta[MI_TE + NRT + t] = NE;
      meta[MI_TR + NRT + t] = SBASE + t * 256;
    }
  }
  __syncthreads();
  for (int e = 0; e < NE; e++) {
    int c = s_cnt[e], b = s_base[e];
    int al = (c + 255) & ~255;
    for (int i = c + threadIdx.x; i < al; i += 256) rowtok[b + i] = -1;
  }
}

// ---------------- scatter tokens into expert buckets (+slot record) ---------
__global__ __launch_bounds__(256) void k_scatter(const int* __restrict__ te0,
                                                 const int* __restrict__ te1,
                                                 int* __restrict__ meta,
                                                 int* __restrict__ rowtok,
                                                 int* __restrict__ sl0,
                                                 int* __restrict__ sl1) {
  int t = blockIdx.x * 256 + threadIdx.x;
  int e0 = te0[t], e1 = te1[t];
  int p0 = atomicAdd(&meta[MI_CUR + e0], 1);
  int r0 = meta[MI_BASE + e0] + p0;
  rowtok[r0] = t; sl0[t] = r0;
  int p1 = atomicAdd(&meta[MI_CUR + e1], 1);
  int r1 = meta[MI_BASE + e1] + p1;
  rowtok[r1] = t; sl1[t] = r1;
}

// ======= GEMM1: H = silu(X Wg) * (X Wu) over interleaved WGU ================
// 256 rows x 256 n'-cols, BK=64, 512 thr (8 waves: 2m x 4n), dbuf LDS,
// counted-vmcnt pipeline, XOR-swizzled LDS (chunk ^= row&7).
__global__ __launch_bounds__(512, 2) void k_gemm1p(const F16* __restrict__ xh,
                                                   const F16* __restrict__ wgu,
                                                   F16* __restrict__ H,
                                                   const int* __restrict__ meta,
                                                   const int* __restrict__ rowtok) {
  const int e = meta[MI_TE + blockIdx.y];
  if (e < 0) return;
  const int row0 = meta[MI_TR + blockIdx.y];
  const int n0 = blockIdx.x * 256;
  const F16* WB = wgu + (size_t)e * (2 * FF) * C;
  __shared__ __align__(16) F16 sA[2][256 * 64];
  __shared__ __align__(16) F16 sB[2][256 * 64];
  const int tid = threadIdx.x, lane = tid & 63, wid = tid >> 6;
  const int wm = wid >> 2, wn = wid & 3;

  // staging: thread t -> row tid>>3 (+64*i), source chunk pre-swizzled
  const int srow = tid >> 3;
  const int scol = ((tid & 7) ^ (srow & 7)) << 3;
  const F16 *pa[4], *pb[4];
#pragma unroll
  for (int i = 0; i < 4; ++i) {
    const int r = i * 64 + srow;
    int tok = (e == NE) ? (row0 - SBASE + r) : rowtok[row0 + r];
    if (tok < 0) tok = 0;   // pad row: harmless dup, weight never used
    pa[i] = xh + (size_t)tok * C + scol;
    pb[i] = WB + (size_t)(n0 + r) * C + scol;
  }
  const int ldsrow = wid * 8;

  // prologue: stage K-tile 0
#pragma unroll
  for (int i = 0; i < 4; ++i) {
    gload16(pa[i], &sA[0][(i * 64 + ldsrow) * 64]);
    gload16(pb[i], &sB[0][(i * 64 + ldsrow) * 64]);
  }

  f32x4 acc[8][4];
  const f32x4 fz = {0.f, 0.f, 0.f, 0.f};
#pragma unroll
  for (int i = 0; i < 8; ++i)
#pragma unroll
    for (int j = 0; j < 4; ++j) acc[i][j] = fz;

  const int fro = lane & 15, q = lane >> 4, xs = fro & 7;
  int aoff[8], boff[4];
#pragma unroll
  for (int mi = 0; mi < 8; ++mi)
    aoff[mi] = (wm * 128 + mi * 16 + fro) * 64 + ((q ^ xs) << 3);
#pragma unroll
  for (int ni = 0; ni < 4; ++ni)
    boff[ni] = (wn * 64 + ni * 16 + fro) * 64 + ((q ^ xs) << 3);

  constexpr int NT = C / 64;  // 16
  for (int t = 0; t < NT; ++t) {
    const int cur = t & 1, nxt = cur ^ 1;
    const bool last = (t == NT - 1);
    const int k1 = (t + 1) * 64;
    const F16* sAc = sA[cur];
    const F16* sBc = sB[cur];
    if (!last) {
      gload16(pa[0] + k1, &sA[nxt][ldsrow * 64]);
      gload16(pb[0] + k1, &sB[nxt][ldsrow * 64]);
    }
    SCHB();
    if (last) vmcnt0(); else vmcnt2();   // drain tile t, keep t+1 in flight
    SCHB();
    BARR();                              // tile t visible to all waves

    f16x8 bb[4][2];
#pragma unroll
    for (int ni = 0; ni < 4; ++ni) {
      bb[ni][0] = *(const f16x8*)&sBc[boff[ni]];
      bb[ni][1] = *(const f16x8*)&sBc[boff[ni] ^ 32];
    }
#pragma unroll
    for (int p = 0; p < 4; ++p) {
      const int m0 = 2 * p, m1 = 2 * p + 1;
      f16x8 a0k0 = *(const f16x8*)&sAc[aoff[m0]];
      f16x8 a0k1 = *(const f16x8*)&sAc[aoff[m0] ^ 32];
      f16x8 a1k0 = *(const f16x8*)&sAc[aoff[m1]];
      f16x8 a1k1 = *(const f16x8*)&sAc[aoff[m1] ^ 32];
      if (!last && p < 3) {
        gload16(pa[p + 1] + k1, &sA[nxt][((p + 1) * 64 + ldsrow) * 64]);
        gload16(pb[p + 1] + k1, &sB[nxt][((p + 1) * 64 + ldsrow) * 64]);
      }
      BARR();
      lgkm0();
      SCHB();
      __builtin_amdgcn_s_setprio(1);
#pragma unroll
      for (int ni = 0; ni < 4; ++ni) {
        acc[m0][ni] = __builtin_amdgcn_mfma_f32_16x16x32_f16(a0k0, bb[ni][0], acc[m0][ni], 0, 0, 0);
        acc[m1][ni] = __builtin_amdgcn_mfma_f32_16x16x32_f16(a1k0, bb[ni][0], acc[m1][ni], 0, 0, 0);
      }
#pragma unroll
      for (int ni = 0; ni < 4; ++ni) {
        acc[m0][ni] = __builtin_amdgcn_mfma_f32_16x16x32_f16(a0k1, bb[ni][1], acc[m0][ni], 0, 0, 0);
        acc[m1][ni] = __builtin_amdgcn_mfma_f32_16x16x32_f16(a1k1, bb[ni][1], acc[m1][ni], 0, 0, 0);
      }
      __builtin_amdgcn_s_setprio(0);
      SCHB();
      BARR();
    }
  }

  // epilogue: pair (ni even=gate, ni odd=up) -> silu fuse -> H f16
  const int erow = (lane >> 4) << 2, ecol = lane & 15;
  const int hb = (n0 >> 1) + wn * 32;
#pragma unroll
  for (int mi = 0; mi < 8; ++mi)
#pragma unroll
    for (int pp = 0; pp < 2; ++pp)
#pragma unroll
      for (int j = 0; j < 4; ++j) {
        const int grow = row0 + wm * 128 + mi * 16 + erow + j;
        const float gv = acc[mi][2 * pp][j], uv = acc[mi][2 * pp + 1][j];
        const float h = gv / (1.f + __expf(-gv)) * uv;
        H[(size_t)grow * FF + hb + pp * 16 + ecol] = (F16)h;
      }
}

// ======= GEMM2: Y = H Wd (row-indexed, combine later) =======================
// 256 rows x 128 cols, BK=64, 512 thr (2m x 4n waves), same pipeline.
__global__ __launch_bounds__(512, 2) void k_gemm2p(const F16* __restrict__ H,
                                                   const F16* __restrict__ wd,
                                                   F16* __restrict__ Y,
                                                   const int* __restrict__ meta) {
  const int e = meta[MI_TE + blockIdx.y];
  if (e < 0) return;
  const int row0 = meta[MI_TR + blockIdx.y];
  const int n0 = blockIdx.x * 128;
  const F16* WB = wd + (size_t)e * C * FF;
  __shared__ __align__(16) F16 sA[2][256 * 64];
  __shared__ __align__(16) F16 sB[2][128 * 64];
  const int tid = threadIdx.x, lane = tid & 63, wid = tid >> 6;
  const int wm = wid >> 2, wn = wid & 3;
  const int srow = tid >> 3;
  const int scol = ((tid & 7) ^ (srow & 7)) << 3;
  const F16 *pa[4], *pb[2];
#pragma unroll
  for (int i = 0; i < 4; ++i)
    pa[i] = H + (size_t)(row0 + i * 64 + srow) * FF + scol;
#pragma unroll
  for (int i = 0; i < 2; ++i)
    pb[i] = WB + (size_t)(n0 + i * 64 + srow) * FF + scol;
  const int ldsrow = wid * 8;

#pragma unroll
  for (int i = 0; i < 4; ++i) gload16(pa[i], &sA[0][(i * 64 + ldsrow) * 64]);
#pragma unroll
  for (int i = 0; i < 2; ++i) gload16(pb[i], &sB[0][(i * 64 + ldsrow) * 64]);

  f32x4 acc[8][2];
  const f32x4 fz = {0.f, 0.f, 0.f, 0.f};
#pragma unroll
  for (int i = 0; i < 8; ++i) { acc[i][0] = fz; acc[i][1] = fz; }

  const int fro = lane & 15, q = lane >> 4, xs = fro & 7;
  int aoff[8], boff[2];
#pragma unroll
  for (int mi = 0; mi < 8; ++mi)
    aoff[mi] = (wm * 128 + mi * 16 + fro) * 64 + ((q ^ xs) << 3);
#pragma unroll
  for (int ni = 0; ni < 2; ++ni)
    boff[ni] = (wn * 32 + ni * 16 + fro) * 64 + ((q ^ xs) << 3);

  constexpr int NT = FF / 64;  // 32
  for (int t = 0; t < NT; ++t) {
    const int cur = t & 1, nxt = cur ^ 1;
    const bool last = (t == NT - 1);
    const int k1 = (t + 1) * 64;
    const F16* sAc = sA[cur];
    const F16* sBc = sB[cur];
    if (!last) {
      gload16(pa[0] + k1, &sA[nxt][ldsrow * 64]);
      gload16(pb[0] + k1, &sB[nxt][ldsrow * 64]);
    }
    SCHB();
    if (last) vmcnt0(); else vmcnt2();
    SCHB();
    BARR();

    f16x8 bb[2][2];
#pragma unroll
    for (int ni = 0; ni < 2; ++ni) {
      bb[ni][0] = *(const f16x8*)&sBc[boff[ni]];
      bb[ni][1] = *(const f16x8*)&sBc[boff[ni] ^ 32];
    }
#pragma unroll
    for (int p = 0; p < 2; ++p) {
      f16x8 aa[4][2];
#pragma unroll
      for (int i = 0; i < 4; ++i) {
        aa[i][0] = *(const f16x8*)&sAc[aoff[p * 4 + i]];
        aa[i][1] = *(const f16x8*)&sAc[aoff[p * 4 + i] ^ 32];
      }
      if (!last) {
        if (p == 0) {
          gload16(pa[1] + k1, &sA[nxt][(64 + ldsrow) * 64]);
          gload16(pa[2] + k1, &sA[nxt][(128 + ldsrow) * 64]);
        } else {
          gload16(pa[3] + k1, &sA[nxt][(192 + ldsrow) * 64]);
          gload16(pb[1] + k1, &sB[nxt][(64 + ldsrow) * 64]);
        }
      }
      BARR();
      lgkm0();
      SCHB();
      __builtin_amdgcn_s_setprio(1);
#pragma unroll
      for (int i = 0; i < 4; ++i)
#pragma unroll
        for (int ni = 0; ni < 2; ++ni) {
          acc[p * 4 + i][ni] = __builtin_amdgcn_mfma_f32_16x16x32_f16(aa[i][0], bb[ni][0], acc[p * 4 + i][ni], 0, 0, 0);
          acc[p * 4 + i][ni] = __builtin_amdgcn_mfma_f32_16x16x32_f16(aa[i][1], bb[ni][1], acc[p * 4 + i][ni], 0, 0, 0);
        }
      __builtin_amdgcn_s_setprio(0);
      SCHB();
      BARR();
    }
  }

  const int erow = (lane >> 4) << 2, ecol = lane & 15;
#pragma unroll
  for (int mi = 0; mi < 8; ++mi)
#pragma unroll
    for (int ni = 0; ni < 2; ++ni)
#pragma unroll
      for (int j = 0; j < 4; ++j) {
        const int grow = row0 + wm * 128 + mi * 16 + erow + j;
        Y[(size_t)grow * C + n0 + wn * 32 + ni * 16 + ecol] = (F16)acc[mi][ni][j];
      }
}

// ---------------- combine: out = w0*Y[r0] + w1*Y[r1] + Y[shared] ------------
__global__ __launch_bounds__(256) void k_combine(const F16* __restrict__ Y,
                                                 const int* __restrict__ sl0,
                                                 const int* __restrict__ sl1,
                                                 const float* __restrict__ tw0,
                                                 const float* __restrict__ tw1,
                                                 float* __restrict__ out) {
  int idx = blockIdx.x * 256 + threadIdx.x;   // token*128 + colgroup
  int t = idx >> 7, cg = idx & 127;
  int r0 = sl0[t], r1 = sl1[t];
  float w0 = tw0[t], w1 = tw1[t];
  f16x8 y0 = *(const f16x8*)&Y[(size_t)r0 * C + cg * 8];
  f16x8 y1 = *(const f16x8*)&Y[(size_t)r1 * C + cg * 8];
  f16x8 ys = *(const f16x8*)&Y[(size_t)(SBASE + t) * C + cg * 8];
  float o[8];
#pragma unroll
  for (int j = 0; j < 8; j++)
    o[j] = w0 * (float)y0[j] + w1 * (float)y1[j] + (float)ys[j];
  float* op = out + (size_t)t * C + cg * 8;
  ((float4*)op)[0] = make_float4(o[0], o[1], o[2], o[3]);
  ((float4*)op)[1] = make_float4(o[4], o[5], o[6], o[7]);
}

// ---------------- host launch ----------------
extern "C" void kernel_launch(void* const* d_in, const int* in_sizes, int n_in,
                              void* d_out, int out_size, void* d_ws, size_t ws_size,
                              hipStream_t stream) {
  const float* x  = (const float*)d_in[0];
  const float* rw = (const float*)d_in[1];
  const float* wgate = (const float*)d_in[2];
  const float* wup   = (const float*)d_in[3];
  const float* wdown = (const float*)d_in[4];
  const float* sg = (const float*)d_in[5];
  const float* su = (const float*)d_in[6];
  const float* sd = (const float*)d_in[7];
  float* out = (float*)d_out;

  char* ws = (char*)d_ws;
  size_t o = 0;
  auto alloc = [&](size_t bytes) -> void* {
    void* p = ws + o;
    o += (bytes + 255) & ~(size_t)255;
    return p;
  };
  F16* xh  = (F16*)alloc((size_t)NTOK * C * 2);
  F16* WGU = (F16*)alloc((size_t)9 * 2 * FF * C * 2);
  F16* WD  = (F16*)alloc((size_t)9 * C * FF * 2);
  F16* Hb  = (F16*)alloc((size_t)ROWS * FF * 2);
  int* rowtok = (int*)alloc((size_t)SBASE * 4);
  int* meta = (int*)alloc(2048);
  int* te0 = (int*)alloc((size_t)NTOK * 4);
  int* te1 = (int*)alloc((size_t)NTOK * 4);
  float* tw0 = (float*)alloc((size_t)NTOK * 4);
  float* tw1 = (float*)alloc((size_t)NTOK * 4);
  int* sl0 = (int*)alloc((size_t)NTOK * 4);
  int* sl1 = (int*)alloc((size_t)NTOK * 4);
  if (o > ws_size) return;  // workspace too small: visible clean failure
  F16* Yb = WGU;            // overlay: WGU dead after gemm1, Y (54.5MB) < WGU (75.5MB)

  hipMemsetAsync(meta, 0, 1024, stream);
  k_cast_x<<<NTOK * C / 1024, 256, 0, stream>>>(x, xh);
  k_cast_w<1><<<dim3(FF / 32, C / 64, 18), 256, 0, stream>>>(wgate, sg, wup, su, WGU, C, FF);
  k_cast_w<0><<<dim3(C / 32, FF / 64, 9), 256, 0, stream>>>(wdown, sd, nullptr, nullptr, WD, FF, C);
  k_router<<<NTOK / 4, 256, 0, stream>>>(x, rw, meta, te0, te1, tw0, tw1);
  k_scan<<<1, 256, 0, stream>>>(meta, rowtok);
  k_scatter<<<NTOK / 256, 256, 0, stream>>>(te0, te1, meta, rowtok, sl0, sl1);
  k_gemm1p<<<dim3(2 * FF / 256, MAXT), 512, 0, stream>>>(xh, WGU, Hb, meta, rowtok);
  k_gemm2p<<<dim3(C / 128, MAXT), 512, 0, stream>>>(Hb, WD, Yb, meta);
  k_combine<<<NTOK * (C / 8) / 256, 256, 0, stream>>>(Yb, sl0, sl1, tw0, tw1, out);
}

// Round 3
// 775.764 us; speedup vs baseline: 1.0975x; 1.0740x over previous
//
#include <hip/hip_runtime.h>

typedef _Float16 F16;
typedef __attribute__((ext_vector_type(8))) _Float16 f16x8;
typedef __attribute__((ext_vector_type(4))) _Float16 f16x4;
typedef __attribute__((ext_vector_type(4))) float f32x4;

constexpr int NTOK = 8192;   // B*T
constexpr int C    = 1024;   // d_model
constexpr int FF   = 2048;   // d_ff
constexpr int NE   = 8;      // experts
constexpr int NRT  = 72;     // max routed 256-row tiles: 16384/256 + 8
constexpr int NST  = 32;     // shared-expert tiles: 8192/256
constexpr int MAXT = NRT + NST;     // 104
constexpr int SBASE = NRT * 256;    // 18432: shared rows start here in H/Y
constexpr int ROWS = SBASE + NTOK;  // 26624

#define MI_CNT 0
#define MI_CUR 8
#define MI_BASE 16
#define MI_TE 32
#define MI_TR (32 + MAXT)

__device__ __forceinline__ void gload16(const void* g, void* l) {
  __builtin_amdgcn_global_load_lds(
      (__attribute__((address_space(1))) void*)g,
      (__attribute__((address_space(3))) void*)l, 16, 0, 0);
}
#define VMCNT8() asm volatile("s_waitcnt vmcnt(8)" ::: "memory")
#define VMCNT0() asm volatile("s_waitcnt vmcnt(0)" ::: "memory")
#define LGKM4()  asm volatile("s_waitcnt lgkmcnt(4)" ::: "memory")
#define LGKM0()  asm volatile("s_waitcnt lgkmcnt(0)" ::: "memory")
#define SCHB()   __builtin_amdgcn_sched_barrier(0)
#define BARR()   __builtin_amdgcn_s_barrier()
#define PRIO1()  __builtin_amdgcn_s_setprio(1)
#define PRIO0()  __builtin_amdgcn_s_setprio(0)

// ---------------- cast x (fp32 -> fp16) ----------------
__global__ __launch_bounds__(256) void k_cast_x(const float* __restrict__ x,
                                                F16* __restrict__ xh) {
  int i = blockIdx.x * blockDim.x + threadIdx.x;
  float4 v = ((const float4*)x)[i];
  f16x4 o;
  o.x = (F16)v.x; o.y = (F16)v.y; o.z = (F16)v.z; o.w = (F16)v.w;
  ((f16x4*)xh)[i] = o;
}

// ------- transpose+cast: src [K][N] fp32 -> dst [N'][K] fp16 ----------------
// MODE 0: N'=N (w_down). MODE 1: gate/up 16-col interleave into WGU:
//   n' = ((n>>4)<<5) | (sel<<4) | (n&15);  z = e*2+sel, e==8 -> shared weights
template <int MODE>
__global__ __launch_bounds__(256) void k_cast_w(const float* __restrict__ w8a,
                                                const float* __restrict__ w1a,
                                                const float* __restrict__ w8b,
                                                const float* __restrict__ w1b,
                                                F16* __restrict__ dst, int K, int N) {
  int z = blockIdx.z;
  const float* src; F16* d; int sel = 0;
  if (MODE == 1) {
    int e = z >> 1; sel = z & 1;
    src = sel ? ((e < NE) ? w8b + (size_t)e * K * N : w1b)
              : ((e < NE) ? w8a + (size_t)e * K * N : w1a);
    d = dst + (size_t)e * 2 * N * K;
  } else {
    src = (z < NE) ? (w8a + (size_t)z * K * N) : w1a;
    d = dst + (size_t)z * N * K;
  }
  __shared__ float t[64][33];
  int n0 = blockIdx.x * 32, k0 = blockIdx.y * 64;
  int tx = threadIdx.x & 31, ty = threadIdx.x >> 5;
#pragma unroll
  for (int i = 0; i < 8; i++)
    t[ty + i * 8][tx] = src[(size_t)(k0 + ty + i * 8) * N + n0 + tx];
  __syncthreads();
  int wx = threadIdx.x & 63, wy = threadIdx.x >> 6;
#pragma unroll
  for (int i = 0; i < 8; i++) {
    int n = n0 + wy + i * 4;
    size_t row = (MODE == 1) ? (size_t)(((n >> 4) << 5) | (sel << 4) | (n & 15))
                             : (size_t)n;
    d[row * K + k0 + wx] = (F16)t[wx][wy + i * 4];
  }
}

// ---------------- router: fp64 logits, top-2, softmax ----------------
__global__ __launch_bounds__(256) void k_router(const float* __restrict__ x,
                                                const float* __restrict__ rw,
                                                int* __restrict__ meta,
                                                int* __restrict__ te0, int* __restrict__ te1,
                                                float* __restrict__ tw0, float* __restrict__ tw1) {
  __shared__ float lrw[NE * C];
  for (int i = threadIdx.x; i < NE * C / 4; i += 256)
    ((float4*)lrw)[i] = ((const float4*)rw)[i];
  __syncthreads();
  int lane = threadIdx.x & 63, wid = threadIdx.x >> 6;
  int t = blockIdx.x * 4 + wid;
  const float* xr = x + (size_t)t * C;
  float xv[16];
#pragma unroll
  for (int i = 0; i < 4; i++) {
    float4 v = ((const float4*)xr)[lane * 4 + i];
    xv[i * 4 + 0] = v.x; xv[i * 4 + 1] = v.y; xv[i * 4 + 2] = v.z; xv[i * 4 + 3] = v.w;
  }
  double lg[NE];
#pragma unroll
  for (int e = 0; e < NE; e++) {
    double s = 0.0;
#pragma unroll
    for (int i = 0; i < 16; i++)
      s += (double)xv[i] * (double)lrw[e * C + lane * 16 + i];
#pragma unroll
    for (int d = 1; d < 64; d <<= 1) s += __shfl_xor(s, d, 64);
    lg[e] = s;
  }
  double b0 = -1e300; int i0 = 0;
#pragma unroll
  for (int e = 0; e < NE; e++) if (lg[e] > b0) { b0 = lg[e]; i0 = e; }
  double b1 = -1e300; int i1 = 0;
#pragma unroll
  for (int e = 0; e < NE; e++) if (e != i0 && lg[e] > b1) { b1 = lg[e]; i1 = e; }
  float ex = __expf((float)(b1 - b0));
  float w0 = 1.f / (1.f + ex), w1 = ex / (1.f + ex);
  if (lane == 0) {
    te0[t] = i0; te1[t] = i1; tw0[t] = w0; tw1[t] = w1;
    atomicAdd(&meta[MI_CNT + i0], 1);
    atomicAdd(&meta[MI_CNT + i1], 1);
  }
}

// ---------------- scan: bases, tile map (routed + shared), pad fill ----------
__global__ __launch_bounds__(256) void k_scan(int* __restrict__ meta,
                                              int* __restrict__ rowtok) {
  __shared__ int s_cnt[NE], s_base[NE];
  if (threadIdx.x == 0) {
    int b = 0, nt = 0;
    for (int e = 0; e < NE; e++) {
      int c = meta[MI_CNT + e];
      s_cnt[e] = c; s_base[e] = b;
      meta[MI_BASE + e] = b;
      meta[MI_CUR + e] = 0;
      int tiles = (c + 255) >> 8;
      for (int t = 0; t < tiles; t++) {
        meta[MI_TE + nt] = e;
        meta[MI_TR + nt] = b + t * 256;
        nt++;
      }
      b += tiles << 8;
    }
    for (int t = nt; t < NRT; t++) meta[MI_TE + t] = -1;
    for (int t = 0; t < NST; t++) {
      meta[MI_TE + NRT + t] = NE;
      meta[MI_TR + NRT + t] = SBASE + t * 256;
    }
  }
  __syncthreads();
  for (int e = 0; e < NE; e++) {
    int c = s_cnt[e], b = s_base[e];
    int al = (c + 255) & ~255;
    for (int i = c + threadIdx.x; i < al; i += 256) rowtok[b + i] = -1;
  }
}

// ---------------- scatter tokens into expert buckets (+slot record) ---------
__global__ __launch_bounds__(256) void k_scatter(const int* __restrict__ te0,
                                                 const int* __restrict__ te1,
                                                 int* __restrict__ meta,
                                                 int* __restrict__ rowtok,
                                                 int* __restrict__ sl0,
                                                 int* __restrict__ sl1) {
  int t = blockIdx.x * 256 + threadIdx.x;
  int e0 = te0[t], e1 = te1[t];
  int p0 = atomicAdd(&meta[MI_CUR + e0], 1);
  int r0 = meta[MI_BASE + e0] + p0;
  rowtok[r0] = t; sl0[t] = r0;
  int p1 = atomicAdd(&meta[MI_CUR + e1], 1);
  int r1 = meta[MI_BASE + e1] + p1;
  rowtok[r1] = t; sl1[t] = r1;
}

// ============ fused MFMA helpers ============
__device__ __forceinline__ void read_a(f16x8 (&ar)[2][2], const F16* sAc,
                                       const int* aoff, int m0) {
  ar[0][0] = *(const f16x8*)&sAc[aoff[m0]];
  ar[0][1] = *(const f16x8*)&sAc[aoff[m0] ^ 32];
  ar[1][0] = *(const f16x8*)&sAc[aoff[m0 + 1]];
  ar[1][1] = *(const f16x8*)&sAc[aoff[m0 + 1] ^ 32];
}
__device__ __forceinline__ void mfma_pair(f32x4 (&a0)[4], f32x4 (&a1)[4],
                                          const f16x8 (&ar)[2][2],
                                          const f16x8 (&bb)[4][2]) {
#pragma unroll
  for (int ni = 0; ni < 4; ++ni) {
    a0[ni] = __builtin_amdgcn_mfma_f32_16x16x32_f16(ar[0][0], bb[ni][0], a0[ni], 0, 0, 0);
    a1[ni] = __builtin_amdgcn_mfma_f32_16x16x32_f16(ar[1][0], bb[ni][0], a1[ni], 0, 0, 0);
  }
#pragma unroll
  for (int ni = 0; ni < 4; ++ni) {
    a0[ni] = __builtin_amdgcn_mfma_f32_16x16x32_f16(ar[0][1], bb[ni][1], a0[ni], 0, 0, 0);
    a1[ni] = __builtin_amdgcn_mfma_f32_16x16x32_f16(ar[1][1], bb[ni][1], a1[ni], 0, 0, 0);
  }
}

// ======= unified 256x256 grouped GEMM, never-drain pipeline =================
// G1: D=silu/up-fused H from gathered x rows vs WGU. !G1: Y = H x WD.
// 8 waves (2m x 4n), per-wave 128x64, BK=64, dbuf LDS, vmcnt(8), 2 barriers/tile.
template <bool G1>
__global__ __launch_bounds__(512, 2) void k_gemm(const F16* __restrict__ Asrc,
                                                 const F16* __restrict__ Wsrc,
                                                 F16* __restrict__ Dst,
                                                 const int* __restrict__ meta,
                                                 const int* __restrict__ rowtok) {
  constexpr int K = G1 ? C : FF;
  constexpr int NT = K / 64;
  const int e = meta[MI_TE + blockIdx.y];
  if (e < 0) return;
  const int row0 = meta[MI_TR + blockIdx.y];
  const int n0 = blockIdx.x * 256;
  const F16* WB = Wsrc + (size_t)e * (size_t)(G1 ? 2 * FF : C) * K;
  __shared__ __align__(16) F16 sA[2][256 * 64];
  __shared__ __align__(16) F16 sB[2][256 * 64];
  const int tid = threadIdx.x, lane = tid & 63, wid = tid >> 6;
  const int wm = wid >> 2, wn = wid & 3;
  const int srow = tid >> 3;
  const int scol = ((tid & 7) ^ (srow & 7)) << 3;   // pre-swizzled global source
  const F16 *pa[4], *pb[4];
#pragma unroll
  for (int i = 0; i < 4; ++i) {
    const int r = i * 64 + srow;
    int arow;
    if (G1) {
      int tok = (e == NE) ? (row0 - SBASE + r) : rowtok[row0 + r];
      if (tok < 0) tok = 0;     // pad row: harmless dup, never combined
      arow = tok;
    } else {
      arow = row0 + r;
    }
    pa[i] = Asrc + (size_t)arow * K + scol;
    pb[i] = WB + (size_t)(n0 + r) * K + scol;
  }
  const int ldsrow = wid * 8;

  // prologue: stage tile 0
#pragma unroll
  for (int i = 0; i < 4; ++i) {
    gload16(pa[i], &sA[0][(i * 64 + ldsrow) * 64]);
    gload16(pb[i], &sB[0][(i * 64 + ldsrow) * 64]);
  }

  f32x4 acc[8][4];
  const f32x4 fz = {0.f, 0.f, 0.f, 0.f};
#pragma unroll
  for (int i = 0; i < 8; ++i)
#pragma unroll
    for (int j = 0; j < 4; ++j) acc[i][j] = fz;

  const int fro = lane & 15, q = lane >> 4, xs = fro & 7;
  int aoff[8], boff[4];
#pragma unroll
  for (int mi = 0; mi < 8; ++mi)
    aoff[mi] = (wm * 128 + mi * 16 + fro) * 64 + ((q ^ xs) << 3);
#pragma unroll
  for (int ni = 0; ni < 4; ++ni)
    boff[ni] = (wn * 64 + ni * 16 + fro) * 64 + ((q ^ xs) << 3);

  for (int t = 0; t < NT; ++t) {
    const int cur = t & 1, nxt = cur ^ 1;
    const F16* sAc = sA[cur];
    const F16* sBc = sB[cur];
    if (t + 1 < NT) {
      const int k1 = (t + 1) * 64;
#pragma unroll
      for (int i = 0; i < 4; ++i) {
        gload16(pa[i] + k1, &sA[nxt][(i * 64 + ldsrow) * 64]);
        gload16(pb[i] + k1, &sB[nxt][(i * 64 + ldsrow) * 64]);
      }
      SCHB();
      VMCNT8();          // tile t complete; tile t+1's 8 stay in flight
    } else {
      VMCNT0();
    }
    SCHB();
    BARR();              // visibility of tile t across waves
    SCHB();

    f16x8 bb[4][2], ax[2][2], ay[2][2];
#pragma unroll
    for (int ni = 0; ni < 4; ++ni) {
      bb[ni][0] = *(const f16x8*)&sBc[boff[ni]];
      bb[ni][1] = *(const f16x8*)&sBc[boff[ni] ^ 32];
    }
    read_a(ax, sAc, aoff, 0);
    SCHB();              // pin issue order: (bb, ax) before ay
    read_a(ay, sAc, aoff, 2);
    SCHB();
    LGKM4(); SCHB();     // bb+ax done (pure-DS in-order retire)
    PRIO1(); mfma_pair(acc[0], acc[1], ax, bb); PRIO0();
    read_a(ax, sAc, aoff, 4);
    SCHB();
    LGKM4(); SCHB();     // ay done
    PRIO1(); mfma_pair(acc[2], acc[3], ay, bb); PRIO0();
    read_a(ay, sAc, aoff, 6);
    SCHB();
    LGKM4(); SCHB();
    PRIO1(); mfma_pair(acc[4], acc[5], ax, bb); PRIO0();
    LGKM0(); SCHB();
    PRIO1(); mfma_pair(acc[6], acc[7], ay, bb); PRIO0();
    SCHB();
    if (t + 1 < NT) BARR();   // read-complete: next iter may overwrite buf cur
  }

  const int erow = (lane >> 4) << 2, ecol = lane & 15;
  if (G1) {
    // pair (ni even=gate, ni odd=up) -> silu fuse -> H f16
    const int hb = (n0 >> 1) + wn * 32;
#pragma unroll
    for (int mi = 0; mi < 8; ++mi)
#pragma unroll
      for (int pp = 0; pp < 2; ++pp)
#pragma unroll
        for (int j = 0; j < 4; ++j) {
          const int grow = row0 + wm * 128 + mi * 16 + erow + j;
          const float gv = acc[mi][2 * pp][j], uv = acc[mi][2 * pp + 1][j];
          const float h = gv / (1.f + __expf(-gv)) * uv;
          Dst[(size_t)grow * FF + hb + pp * 16 + ecol] = (F16)h;
        }
  } else {
#pragma unroll
    for (int mi = 0; mi < 8; ++mi)
#pragma unroll
      for (int ni = 0; ni < 4; ++ni)
#pragma unroll
        for (int j = 0; j < 4; ++j) {
          const int grow = row0 + wm * 128 + mi * 16 + erow + j;
          Dst[(size_t)grow * C + n0 + wn * 64 + ni * 16 + ecol] = (F16)acc[mi][ni][j];
        }
  }
}

// ---------------- combine: out = w0*Y[r0] + w1*Y[r1] + Y[shared] ------------
__global__ __launch_bounds__(256) void k_combine(const F16* __restrict__ Y,
                                                 const int* __restrict__ sl0,
                                                 const int* __restrict__ sl1,
                                                 const float* __restrict__ tw0,
                                                 const float* __restrict__ tw1,
                                                 float* __restrict__ out) {
  int idx = blockIdx.x * 256 + threadIdx.x;
  int t = idx >> 7, cg = idx & 127;
  int r0 = sl0[t], r1 = sl1[t];
  float w0 = tw0[t], w1 = tw1[t];
  f16x8 y0 = *(const f16x8*)&Y[(size_t)r0 * C + cg * 8];
  f16x8 y1 = *(const f16x8*)&Y[(size_t)r1 * C + cg * 8];
  f16x8 ys = *(const f16x8*)&Y[(size_t)(SBASE + t) * C + cg * 8];
  float o[8];
#pragma unroll
  for (int j = 0; j < 8; j++)
    o[j] = w0 * (float)y0[j] + w1 * (float)y1[j] + (float)ys[j];
  float* op = out + (size_t)t * C + cg * 8;
  ((float4*)op)[0] = make_float4(o[0], o[1], o[2], o[3]);
  ((float4*)op)[1] = make_float4(o[4], o[5], o[6], o[7]);
}

// ---------------- host launch ----------------
extern "C" void kernel_launch(void* const* d_in, const int* in_sizes, int n_in,
                              void* d_out, int out_size, void* d_ws, size_t ws_size,
                              hipStream_t stream) {
  const float* x  = (const float*)d_in[0];
  const float* rw = (const float*)d_in[1];
  const float* wgate = (const float*)d_in[2];
  const float* wup   = (const float*)d_in[3];
  const float* wdown = (const float*)d_in[4];
  const float* sg = (const float*)d_in[5];
  const float* su = (const float*)d_in[6];
  const float* sd = (const float*)d_in[7];
  float* out = (float*)d_out;

  char* ws = (char*)d_ws;
  size_t o = 0;
  auto alloc = [&](size_t bytes) -> void* {
    void* p = ws + o;
    o += (bytes + 255) & ~(size_t)255;
    return p;
  };
  F16* xh  = (F16*)alloc((size_t)NTOK * C * 2);
  F16* WGU = (F16*)alloc((size_t)9 * 2 * FF * C * 2);
  F16* WD  = (F16*)alloc((size_t)9 * C * FF * 2);
  F16* Hb  = (F16*)alloc((size_t)ROWS * FF * 2);
  int* rowtok = (int*)alloc((size_t)SBASE * 4);
  int* meta = (int*)alloc(2048);
  int* te0 = (int*)alloc((size_t)NTOK * 4);
  int* te1 = (int*)alloc((size_t)NTOK * 4);
  float* tw0 = (float*)alloc((size_t)NTOK * 4);
  float* tw1 = (float*)alloc((size_t)NTOK * 4);
  int* sl0 = (int*)alloc((size_t)NTOK * 4);
  int* sl1 = (int*)alloc((size_t)NTOK * 4);
  if (o > ws_size) return;
  F16* Yb = WGU;   // overlay: WGU dead after gemm1; Y (54.5MB) < WGU (75.5MB)

  hipMemsetAsync(meta, 0, 1024, stream);
  k_cast_x<<<NTOK * C / 1024, 256, 0, stream>>>(x, xh);
  k_cast_w<1><<<dim3(FF / 32, C / 64, 18), 256, 0, stream>>>(wgate, sg, wup, su, WGU, C, FF);
  k_cast_w<0><<<dim3(C / 32, FF / 64, 9), 256, 0, stream>>>(wdown, sd, nullptr, nullptr, WD, FF, C);
  k_router<<<NTOK / 4, 256, 0, stream>>>(x, rw, meta, te0, te1, tw0, tw1);
  k_scan<<<1, 256, 0, stream>>>(meta, rowtok);
  k_scatter<<<NTOK / 256, 256, 0, stream>>>(te0, te1, meta, rowtok, sl0, sl1);
  k_gemm<true><<<dim3(2 * FF / 256, MAXT), 512, 0, stream>>>(xh, WGU, Hb, meta, rowtok);
  k_gemm<false><<<dim3(C / 256, MAXT), 512, 0, stream>>>(Hb, WD, Yb, meta, rowtok);
  k_combine<<<NTOK * (C / 8) / 256, 256, 0, stream>>>(Yb, sl0, sl1, tw0, tw1, out);
}

// Round 4
// 773.803 us; speedup vs baseline: 1.1002x; 1.0025x over previous
//
#include <hip/hip_runtime.h>

typedef _Float16 F16;
typedef __attribute__((ext_vector_type(8))) _Float16 f16x8;
typedef __attribute__((ext_vector_type(4))) _Float16 f16x4;
typedef __attribute__((ext_vector_type(4))) float f32x4;

constexpr int NTOK = 8192;   // B*T
constexpr int C    = 1024;   // d_model
constexpr int FF   = 2048;   // d_ff
constexpr int NE   = 8;      // experts
constexpr int NRT  = 72;     // max routed 256-row tiles: 16384/256 + 8
constexpr int NST  = 32;     // shared-expert tiles: 8192/256
constexpr int MAXT = NRT + NST;     // 104
constexpr int SBASE = NRT * 256;    // shared rows start here in H/Y
constexpr int ROWS = SBASE + NTOK;  // 26624

#define MI_CNT 0
#define MI_CUR 8
#define MI_BASE 16
#define MI_TE 32
#define MI_TR (32 + MAXT)

__device__ __forceinline__ void gload16(const void* g, void* l) {
  __builtin_amdgcn_global_load_lds(
      (__attribute__((address_space(1))) void*)g,
      (__attribute__((address_space(3))) void*)l, 16, 0, 0);
}
#define VMCNT4() asm volatile("s_waitcnt vmcnt(4)" ::: "memory")
#define VMCNT0() asm volatile("s_waitcnt vmcnt(0)" ::: "memory")
#define LGKM0()  asm volatile("s_waitcnt lgkmcnt(0)" ::: "memory")
#define SCHB()   __builtin_amdgcn_sched_barrier(0)
#define BARR()   __builtin_amdgcn_s_barrier()
#define PRIO1()  __builtin_amdgcn_s_setprio(1)
#define PRIO0()  __builtin_amdgcn_s_setprio(0)

// ---------------- cast x (fp32 -> fp16) ----------------
__global__ __launch_bounds__(256) void k_cast_x(const float* __restrict__ x,
                                                F16* __restrict__ xh) {
  int i = blockIdx.x * blockDim.x + threadIdx.x;
  float4 v = ((const float4*)x)[i];
  f16x4 o;
  o.x = (F16)v.x; o.y = (F16)v.y; o.z = (F16)v.z; o.w = (F16)v.w;
  ((f16x4*)xh)[i] = o;
}

// ------- transpose+cast: src [K][N] fp32 -> dst [N'][K] fp16 ----------------
template <int MODE>
__global__ __launch_bounds__(256) void k_cast_w(const float* __restrict__ w8a,
                                                const float* __restrict__ w1a,
                                                const float* __restrict__ w8b,
                                                const float* __restrict__ w1b,
                                                F16* __restrict__ dst, int K, int N) {
  int z = blockIdx.z;
  const float* src; F16* d; int sel = 0;
  if (MODE == 1) {
    int e = z >> 1; sel = z & 1;
    src = sel ? ((e < NE) ? w8b + (size_t)e * K * N : w1b)
              : ((e < NE) ? w8a + (size_t)e * K * N : w1a);
    d = dst + (size_t)e * 2 * N * K;
  } else {
    src = (z < NE) ? (w8a + (size_t)z * K * N) : w1a;
    d = dst + (size_t)z * N * K;
  }
  __shared__ float t[64][33];
  int n0 = blockIdx.x * 32, k0 = blockIdx.y * 64;
  int tx = threadIdx.x & 31, ty = threadIdx.x >> 5;
#pragma unroll
  for (int i = 0; i < 8; i++)
    t[ty + i * 8][tx] = src[(size_t)(k0 + ty + i * 8) * N + n0 + tx];
  __syncthreads();
  int wx = threadIdx.x & 63, wy = threadIdx.x >> 6;
#pragma unroll
  for (int i = 0; i < 8; i++) {
    int n = n0 + wy + i * 4;
    size_t row = (MODE == 1) ? (size_t)(((n >> 4) << 5) | (sel << 4) | (n & 15))
                             : (size_t)n;
    d[row * K + k0 + wx] = (F16)t[wx][wy + i * 4];
  }
}

// ---------------- router: fp64 logits, top-2, softmax ----------------
__global__ __launch_bounds__(256) void k_router(const float* __restrict__ x,
                                                const float* __restrict__ rw,
                                                int* __restrict__ meta,
                                                int* __restrict__ te0, int* __restrict__ te1,
                                                float* __restrict__ tw0, float* __restrict__ tw1) {
  __shared__ float lrw[NE * C];
  for (int i = threadIdx.x; i < NE * C / 4; i += 256)
    ((float4*)lrw)[i] = ((const float4*)rw)[i];
  __syncthreads();
  int lane = threadIdx.x & 63, wid = threadIdx.x >> 6;
  int t = blockIdx.x * 4 + wid;
  const float* xr = x + (size_t)t * C;
  float xv[16];
#pragma unroll
  for (int i = 0; i < 4; i++) {
    float4 v = ((const float4*)xr)[lane * 4 + i];
    xv[i * 4 + 0] = v.x; xv[i * 4 + 1] = v.y; xv[i * 4 + 2] = v.z; xv[i * 4 + 3] = v.w;
  }
  double lg[NE];
#pragma unroll
  for (int e = 0; e < NE; e++) {
    double s = 0.0;
#pragma unroll
    for (int i = 0; i < 16; i++)
      s += (double)xv[i] * (double)lrw[e * C + lane * 16 + i];
#pragma unroll
    for (int d = 1; d < 64; d <<= 1) s += __shfl_xor(s, d, 64);
    lg[e] = s;
  }
  double b0 = -1e300; int i0 = 0;
#pragma unroll
  for (int e = 0; e < NE; e++) if (lg[e] > b0) { b0 = lg[e]; i0 = e; }
  double b1 = -1e300; int i1 = 0;
#pragma unroll
  for (int e = 0; e < NE; e++) if (e != i0 && lg[e] > b1) { b1 = lg[e]; i1 = e; }
  float ex = __expf((float)(b1 - b0));
  float w0 = 1.f / (1.f + ex), w1 = ex / (1.f + ex);
  if (lane == 0) {
    te0[t] = i0; te1[t] = i1; tw0[t] = w0; tw1[t] = w1;
    atomicAdd(&meta[MI_CNT + i0], 1);
    atomicAdd(&meta[MI_CNT + i1], 1);
  }
}

// ---------------- scan: bases, tile map (routed + shared), pad fill ----------
__global__ __launch_bounds__(256) void k_scan(int* __restrict__ meta,
                                              int* __restrict__ rowtok) {
  __shared__ int s_cnt[NE], s_base[NE];
  if (threadIdx.x == 0) {
    int b = 0, nt = 0;
    for (int e = 0; e < NE; e++) {
      int c = meta[MI_CNT + e];
      s_cnt[e] = c; s_base[e] = b;
      meta[MI_BASE + e] = b;
      meta[MI_CUR + e] = 0;
      int tiles = (c + 255) >> 8;
      for (int t = 0; t < tiles; t++) {
        meta[MI_TE + nt] = e;
        meta[MI_TR + nt] = b + t * 256;
        nt++;
      }
      b += tiles << 8;
    }
    for (int t = nt; t < NRT; t++) meta[MI_TE + t] = -1;
    for (int t = 0; t < NST; t++) {
      meta[MI_TE + NRT + t] = NE;
      meta[MI_TR + NRT + t] = SBASE + t * 256;
    }
  }
  __syncthreads();
  for (int e = 0; e < NE; e++) {
    int c = s_cnt[e], b = s_base[e];
    int al = (c + 255) & ~255;
    for (int i = c + threadIdx.x; i < al; i += 256) rowtok[b + i] = -1;
  }
}

// ---------------- scatter tokens into expert buckets (+slot record) ---------
__global__ __launch_bounds__(256) void k_scatter(const int* __restrict__ te0,
                                                 const int* __restrict__ te1,
                                                 int* __restrict__ meta,
                                                 int* __restrict__ rowtok,
                                                 int* __restrict__ sl0,
                                                 int* __restrict__ sl1) {
  int t = blockIdx.x * 256 + threadIdx.x;
  int e0 = te0[t], e1 = te1[t];
  int p0 = atomicAdd(&meta[MI_CUR + e0], 1);
  int r0 = meta[MI_BASE + e0] + p0;
  rowtok[r0] = t; sl0[t] = r0;
  int p1 = atomicAdd(&meta[MI_CUR + e1], 1);
  int r1 = meta[MI_BASE + e1] + p1;
  rowtok[r1] = t; sl1[t] = r1;
}

// ======= unified 256x256 grouped GEMM — m201-style phase schedule ===========
// BK=32, ring-4 LDS (2-tile prefetch), 2 phases/K-tile, per-phase {8/4 ds_read
// + 2 stage gloads + barrier + lgkm0 + 16 MFMA}, vmcnt(4) once per tile.
// Swizzle: 64B rows, chunk ^= (row ^ row>>2)&3 (bijective, conflict-free).
template <bool G1>
__global__ __launch_bounds__(512, 2) void k_gemm(const F16* __restrict__ Asrc,
                                                 const F16* __restrict__ Wsrc,
                                                 F16* __restrict__ Dst,
                                                 const int* __restrict__ meta,
                                                 const int* __restrict__ rowtok) {
  constexpr int K = G1 ? C : FF;
  constexpr int NT = K / 32;
  const int e = meta[MI_TE + blockIdx.y];
  if (e < 0) return;
  const int row0 = meta[MI_TR + blockIdx.y];
  const int n0 = blockIdx.x * 256;
  const F16* WB = Wsrc + (size_t)e * (size_t)(G1 ? 2 * FF : C) * K;
  __shared__ __align__(16) F16 sA[4][256 * 32];
  __shared__ __align__(16) F16 sB[4][256 * 32];
  const int tid = threadIdx.x, lane = tid & 63, wid = tid >> 6;
  const int wm = wid >> 2, wn = wid & 3;

  // staging: instr i covers rows i*128..i*128+127; thread row tid>>2, chunk tid&3
  const F16 *pa[2], *pb[2];
#pragma unroll
  for (int i = 0; i < 2; ++i) {
    const int rl = i * 128 + (tid >> 2);
    const int cs = (tid & 3) ^ ((rl ^ (rl >> 2)) & 3);   // pre-swizzled source chunk
    int arow;
    if (G1) {
      int tok = (e == NE) ? (row0 - SBASE + rl) : rowtok[row0 + rl];
      if (tok < 0) tok = 0;      // pad row: harmless dup, never combined
      arow = tok;
    } else {
      arow = row0 + rl;
    }
    pa[i] = Asrc + (size_t)arow * K + cs * 8;
    pb[i] = WB + (size_t)(n0 + rl) * K + cs * 8;
  }
  const int sb0 = wid * 16 * 32;            // instr 0 LDS base (elems)
  const int sb1 = (128 + wid * 16) * 32;    // instr 1

  // fragment LDS offsets (swizzled)
  const int fro = lane & 15, q = lane >> 4;
  int aoff[8], boff[4];
#pragma unroll
  for (int f = 0; f < 8; ++f) {
    const int r = wm * 128 + f * 16 + fro;
    aoff[f] = r * 32 + ((q ^ ((r ^ (r >> 2)) & 3)) << 3);
  }
#pragma unroll
  for (int ni = 0; ni < 4; ++ni) {
    const int r = wn * 64 + ni * 16 + fro;
    boff[ni] = r * 32 + ((q ^ ((r ^ (r >> 2)) & 3)) << 3);
  }

  f32x4 acc[8][4];
  const f32x4 fz = {0.f, 0.f, 0.f, 0.f};
#pragma unroll
  for (int i = 0; i < 8; ++i)
#pragma unroll
    for (int j = 0; j < 4; ++j) acc[i][j] = fz;

  // prologue: stage tiles 0 and 1 (per wave: 8 loads, FIFO = tile0 first)
#pragma unroll
  for (int t = 0; t < 2; ++t) {
    gload16(pa[0] + t * 32, &sA[t][sb0]);
    gload16(pa[1] + t * 32, &sA[t][sb1]);
    gload16(pb[0] + t * 32, &sB[t][sb0]);
    gload16(pb[1] + t * 32, &sB[t][sb1]);
  }
  SCHB();
  VMCNT4();          // tile 0 complete; tile 1's 4 in flight
  SCHB();
  BARR();

  for (int t = 0; t < NT; ++t) {
    const F16* sAc = sA[t & 3];
    const F16* sBc = sB[t & 3];
    F16* sAn = sA[(t + 2) & 3];
    F16* sBn = sB[(t + 2) & 3];
    const int k2 = (t + 2) * 32;
    const bool stage = (t + 2 < NT);
    f16x8 bb[4], av[4];

    // ---------- phase A: bb + a[0..3], stage next A-pair, MFMA m-half 0 ----
#pragma unroll
    for (int ni = 0; ni < 4; ++ni) bb[ni] = *(const f16x8*)&sBc[boff[ni]];
#pragma unroll
    for (int f = 0; f < 4; ++f) av[f] = *(const f16x8*)&sAc[aoff[f]];
    if (stage) {
      gload16(pa[0] + k2, &sAn[sb0]);
      gload16(pa[1] + k2, &sAn[sb1]);
    }
    SCHB();
    BARR();
    LGKM0();
    SCHB();
    PRIO1();
#pragma unroll
    for (int f = 0; f < 4; ++f)
#pragma unroll
      for (int ni = 0; ni < 4; ++ni)
        acc[f][ni] = __builtin_amdgcn_mfma_f32_16x16x32_f16(av[f], bb[ni], acc[f][ni], 0, 0, 0);
    PRIO0();
    SCHB();
    BARR();

    // ---------- phase B: a[4..7], stage next B-pair, vmcnt, MFMA m-half 1 --
#pragma unroll
    for (int f = 0; f < 4; ++f) av[f] = *(const f16x8*)&sAc[aoff[4 + f]];
    if (stage) {
      gload16(pb[0] + k2, &sBn[sb0]);
      gload16(pb[1] + k2, &sBn[sb1]);
    }
    SCHB();
    if (stage) { VMCNT4(); } else { VMCNT0(); }   // tile t+1 ready, t+2 in flight
    SCHB();
    BARR();
    LGKM0();
    SCHB();
    PRIO1();
#pragma unroll
    for (int f = 0; f < 4; ++f)
#pragma unroll
      for (int ni = 0; ni < 4; ++ni)
        acc[4 + f][ni] = __builtin_amdgcn_mfma_f32_16x16x32_f16(av[f], bb[ni], acc[4 + f][ni], 0, 0, 0);
    PRIO0();
    SCHB();
    BARR();
  }

  const int erow = (lane >> 4) << 2, ecol = lane & 15;
  if (G1) {
    // pair (ni even=gate, ni odd=up) -> silu fuse -> H f16
    const int hb = (n0 >> 1) + wn * 32;
#pragma unroll
    for (int mi = 0; mi < 8; ++mi)
#pragma unroll
      for (int pp = 0; pp < 2; ++pp)
#pragma unroll
        for (int j = 0; j < 4; ++j) {
          const int grow = row0 + wm * 128 + mi * 16 + erow + j;
          const float gv = acc[mi][2 * pp][j], uv = acc[mi][2 * pp + 1][j];
          const float h = gv / (1.f + __expf(-gv)) * uv;
          Dst[(size_t)grow * FF + hb + pp * 16 + ecol] = (F16)h;
        }
  } else {
#pragma unroll
    for (int mi = 0; mi < 8; ++mi)
#pragma unroll
      for (int ni = 0; ni < 4; ++ni)
#pragma unroll
        for (int j = 0; j < 4; ++j) {
          const int grow = row0 + wm * 128 + mi * 16 + erow + j;
          Dst[(size_t)grow * C + n0 + wn * 64 + ni * 16 + ecol] = (F16)acc[mi][ni][j];
        }
  }
}

// ---------------- combine: out = w0*Y[r0] + w1*Y[r1] + Y[shared] ------------
__global__ __launch_bounds__(256) void k_combine(const F16* __restrict__ Y,
                                                 const int* __restrict__ sl0,
                                                 const int* __restrict__ sl1,
                                                 const float* __restrict__ tw0,
                                                 const float* __restrict__ tw1,
                                                 float* __restrict__ out) {
  int idx = blockIdx.x * 256 + threadIdx.x;
  int t = idx >> 7, cg = idx & 127;
  int r0 = sl0[t], r1 = sl1[t];
  float w0 = tw0[t], w1 = tw1[t];
  f16x8 y0 = *(const f16x8*)&Y[(size_t)r0 * C + cg * 8];
  f16x8 y1 = *(const f16x8*)&Y[(size_t)r1 * C + cg * 8];
  f16x8 ys = *(const f16x8*)&Y[(size_t)(SBASE + t) * C + cg * 8];
  float o[8];
#pragma unroll
  for (int j = 0; j < 8; j++)
    o[j] = w0 * (float)y0[j] + w1 * (float)y1[j] + (float)ys[j];
  float* op = out + (size_t)t * C + cg * 8;
  ((float4*)op)[0] = make_float4(o[0], o[1], o[2], o[3]);
  ((float4*)op)[1] = make_float4(o[4], o[5], o[6], o[7]);
}

// ---------------- host launch ----------------
extern "C" void kernel_launch(void* const* d_in, const int* in_sizes, int n_in,
                              void* d_out, int out_size, void* d_ws, size_t ws_size,
                              hipStream_t stream) {
  const float* x  = (const float*)d_in[0];
  const float* rw = (const float*)d_in[1];
  const float* wgate = (const float*)d_in[2];
  const float* wup   = (const float*)d_in[3];
  const float* wdown = (const float*)d_in[4];
  const float* sg = (const float*)d_in[5];
  const float* su = (const float*)d_in[6];
  const float* sd = (const float*)d_in[7];
  float* out = (float*)d_out;

  char* ws = (char*)d_ws;
  size_t o = 0;
  auto alloc = [&](size_t bytes) -> void* {
    void* p = ws + o;
    o += (bytes + 255) & ~(size_t)255;
    return p;
  };
  F16* xh  = (F16*)alloc((size_t)NTOK * C * 2);
  F16* WGU = (F16*)alloc((size_t)9 * 2 * FF * C * 2);
  F16* WD  = (F16*)alloc((size_t)9 * C * FF * 2);
  F16* Hb  = (F16*)alloc((size_t)ROWS * FF * 2);
  int* rowtok = (int*)alloc((size_t)SBASE * 4);
  int* meta = (int*)alloc(2048);
  int* te0 = (int*)alloc((size_t)NTOK * 4);
  int* te1 = (int*)alloc((size_t)NTOK * 4);
  float* tw0 = (float*)alloc((size_t)NTOK * 4);
  float* tw1 = (float*)alloc((size_t)NTOK * 4);
  int* sl0 = (int*)alloc((size_t)NTOK * 4);
  int* sl1 = (int*)alloc((size_t)NTOK * 4);
  if (o > ws_size) return;
  F16* Yb = WGU;   // overlay: WGU dead after gemm1; Y (54.5MB) < WGU (75.5MB)

  hipMemsetAsync(meta, 0, 1024, stream);
  k_cast_x<<<NTOK * C / 1024, 256, 0, stream>>>(x, xh);
  k_cast_w<1><<<dim3(FF / 32, C / 64, 18), 256, 0, stream>>>(wgate, sg, wup, su, WGU, C, FF);
  k_cast_w<0><<<dim3(C / 32, FF / 64, 9), 256, 0, stream>>>(wdown, sd, nullptr, nullptr, WD, FF, C);
  k_router<<<NTOK / 4, 256, 0, stream>>>(x, rw, meta, te0, te1, tw0, tw1);
  k_scan<<<1, 256, 0, stream>>>(meta, rowtok);
  k_scatter<<<NTOK / 256, 256, 0, stream>>>(te0, te1, meta, rowtok, sl0, sl1);
  k_gemm<true><<<dim3(2 * FF / 256, MAXT), 512, 0, stream>>>(xh, WGU, Hb, meta, rowtok);
  k_gemm<false><<<dim3(C / 256, MAXT), 512, 0, stream>>>(Hb, WD, Yb, meta, rowtok);
  k_combine<<<NTOK * (C / 8) / 256, 256, 0, stream>>>(Yb, sl0, sl1, tw0, tw1, out);
}